// Round 1
// baseline (346.674 us; speedup 1.0000x reference)
//
#include <hip/hip_runtime.h>
#include <math.h>

// Problem constants (MoEGate: B=4,T=4096,C=2048,E=64,K=8)
#define NTOK  16384
#define CDIM  2048
#define NEXP  64
#define TOPK  8

#define BM 64      // tokens per block
#define BK 32      // k-tile
#define LDPAD 4    // pad rows to 36 floats (keeps 16B alignment for float4 LDS reads)

// Fused kernel: fp32 tiled GEMM (logits for all 64 experts) + top-8 + sigmoid
// + normalize + per-block expert counts.
__global__ __launch_bounds__(256) void gate_topk_kernel(
    const float* __restrict__ x,        // [NTOK, CDIM]
    const int*   __restrict__ mask,     // [NTOK] (bool as int32)
    const float* __restrict__ W,        // [NEXP, CDIM]
    const float* __restrict__ gbias,    // [NEXP]
    const float* __restrict__ ebias,    // [NEXP]
    float*       __restrict__ out,      // [2*NTOK*TOPK + 1]
    unsigned int* __restrict__ counts)  // [NEXP] global, pre-zeroed
{
    __shared__ float As[BM][BK + LDPAD];     // x tile   [m][k]
    __shared__ float Bs[NEXP][BK + LDPAD];   // W tile   [n][k]
    __shared__ float Lg[BM][NEXP + 1];       // logits   [m][n]
    __shared__ float s_gb[NEXP];
    __shared__ float s_eb[NEXP];
    __shared__ unsigned int s_cnt[NEXP];

    const int tid = threadIdx.x;
    const int tx  = tid & 15;        // expert group (4 experts)
    const int ty  = tid >> 4;        // token group  (4 tokens)
    const int m0  = blockIdx.x * BM; // first token of this block

    if (tid < NEXP) {
        s_gb[tid]  = gbias[tid];
        s_eb[tid]  = ebias[tid];
        s_cnt[tid] = 0u;
    }

    float acc[4][4] = {};

    for (int kb = 0; kb < CDIM; kb += BK) {
        __syncthreads();   // protect LDS from previous iteration's readers
        // ---- load x tile: 64 tokens x 32 k = 2048 floats, 2 passes of 256xfloat4
        #pragma unroll
        for (int p = 0; p < 2; p++) {
            int lin = tid + p * 256;           // 0..511
            int m   = lin >> 3;                // 8 float4 per row
            int c4  = (lin & 7) << 2;
            float4 v = *(const float4*)&x[(size_t)(m0 + m) * CDIM + kb + c4];
            *(float4*)&As[m][c4] = v;
        }
        // ---- load W tile: 64 experts x 32 k
        #pragma unroll
        for (int p = 0; p < 2; p++) {
            int lin = tid + p * 256;
            int n   = lin >> 3;
            int c4  = (lin & 7) << 2;
            float4 v = *(const float4*)&W[(size_t)n * CDIM + kb + c4];
            *(float4*)&Bs[n][c4] = v;
        }
        __syncthreads();

        // ---- compute: 4 tokens x 4 experts per thread, float4 LDS reads
        #pragma unroll
        for (int k4 = 0; k4 < BK; k4 += 4) {
            float4 a[4], b[4];
            #pragma unroll
            for (int i = 0; i < 4; i++) a[i] = *(const float4*)&As[ty * 4 + i][k4];
            #pragma unroll
            for (int j = 0; j < 4; j++) b[j] = *(const float4*)&Bs[tx * 4 + j][k4];
            #pragma unroll
            for (int i = 0; i < 4; i++)
                #pragma unroll
                for (int j = 0; j < 4; j++)
                    acc[i][j] += a[i].x * b[j].x + a[i].y * b[j].y
                               + a[i].z * b[j].z + a[i].w * b[j].w;
        }
    }

    __syncthreads();
    // gate_output = x@W.T + gate_bias  -> stage in LDS
    #pragma unroll
    for (int i = 0; i < 4; i++)
        #pragma unroll
        for (int j = 0; j < 4; j++)
            Lg[ty * 4 + i][tx * 4 + j] = acc[i][j] + s_gb[tx * 4 + j];
    __syncthreads();

    // ---- top-8 per token: one thread per token (threads 0..63)
    if (tid < BM) {
        const int g = m0 + tid;
        unsigned long long used = 0ull;
        int   idxs[TOPK];
        float probs[TOPK];
        float psum = 0.0f;

        #pragma unroll
        for (int k = 0; k < TOPK; k++) {
            float best = -INFINITY;
            int   bi   = 0;
            for (int n = 0; n < NEXP; n++) {
                if ((used >> n) & 1ull) continue;
                float v = Lg[tid][n] + s_eb[n];   // selection uses +expert_biases
                if (v > best) { best = v; bi = n; } // strict > => lowest index on tie (JAX)
            }
            used |= (1ull << bi);
            idxs[k] = bi;
            float z = Lg[tid][bi];                 // prob uses gate_output (no ebias)
            float p = 1.0f / (1.0f + expf(-z));
            probs[k] = p;
            psum += p;
        }
        float inv = 1.0f / psum;
        #pragma unroll
        for (int k = 0; k < TOPK; k++) {
            out[(size_t)g * TOPK + k] = (float)idxs[k];                    // indices as f32
            out[(size_t)NTOK * TOPK + (size_t)g * TOPK + k] = probs[k] * inv;
        }
        if (mask[g] != 0) {
            #pragma unroll
            for (int k = 0; k < TOPK; k++)
                atomicAdd(&s_cnt[idxs[k]], 1u);
        }
    }
    __syncthreads();
    if (tid < NEXP && s_cnt[tid] != 0u)
        atomicAdd(&counts[tid], s_cnt[tid]);
}

__global__ void finalize_kernel(const unsigned int* __restrict__ counts,
                                float* __restrict__ out)
{
    const int t = threadIdx.x;   // 64 threads, one wave
    float c  = (float)counts[t];
    float mx = c, sm = c;
    #pragma unroll
    for (int o = 32; o > 0; o >>= 1) {
        mx = fmaxf(mx, __shfl_down(mx, o));
        sm += __shfl_down(sm, o);
    }
    if (t == 0) {
        float avg = sm / (float)NEXP;
        out[2 * NTOK * TOPK] = (mx - avg) / (avg + 1e-5f);
    }
}

extern "C" void kernel_launch(void* const* d_in, const int* in_sizes, int n_in,
                              void* d_out, int out_size, void* d_ws, size_t ws_size,
                              hipStream_t stream)
{
    const float* x     = (const float*)d_in[0];
    const int*   mask  = (const int*)  d_in[1];
    const float* W     = (const float*)d_in[2];
    const float* gbias = (const float*)d_in[3];
    const float* ebias = (const float*)d_in[4];
    float* out = (float*)d_out;
    unsigned int* counts = (unsigned int*)d_ws;

    hipMemsetAsync(d_ws, 0, NEXP * sizeof(unsigned int), stream);
    gate_topk_kernel<<<NTOK / BM, 256, 0, stream>>>(x, mask, W, gbias, ebias, out, counts);
    finalize_kernel<<<1, 64, 0, stream>>>(counts, out);
}

// Round 2
// 271.370 us; speedup vs baseline: 1.2775x; 1.2775x over previous
//
#include <hip/hip_runtime.h>
#include <math.h>

// Problem constants (MoEGate: B=4,T=4096,C=2048,E=64,K=8)
#define NTOK  16384
#define CDIM  2048
#define NEXP  64
#define TOPK  8

// ============================================================================
// Kernel 1: pack W[64][2048] into conflict-free LDS image layout:
//   Wp[kt(64)][kc(8)][j(4)][tx(16)][c(4)]  = W[tx*4+j][kt*32 + kc*4 + c]
// so the GEMM loader is a straight contiguous copy and the compute-phase
// b-reads (fixed kc,j; lanes tx) are contiguous float4s => zero bank conflict.
// ============================================================================
__global__ __launch_bounds__(256) void pack_w_kernel(
    const float* __restrict__ W, float* __restrict__ Wp)
{
    int lin = blockIdx.x * 256 + threadIdx.x;   // float4 id, 0..32767
    int tx = lin & 15;
    int j  = (lin >> 4) & 3;
    int kc = (lin >> 6) & 7;
    int kt = lin >> 9;                          // 0..63
    int e = tx * 4 + j;
    int k = kt * 32 + kc * 4;
    float4 v = *(const float4*)&W[(size_t)e * CDIM + k];
    *(float4*)&Wp[(size_t)lin * 4] = v;
}

// ============================================================================
// Kernel 2: k-split GEMM. Block computes 64 tokens x 64 experts over a
// CDIM/KS k-range; writes fp32 partial logits to ws. Grid = 256*KS blocks
// -> KS blocks/CU -> 4*KS waves/CU.
// ============================================================================
template<int KS>
__global__ __launch_bounds__(256) void gemm_partial_kernel(
    const float* __restrict__ x,       // [NTOK][CDIM]
    const float* __restrict__ Wp,      // packed, 512 KB
    float*       __restrict__ part)    // [KS][NTOK][NEXP]
{
    __shared__ float As[64][36];       // x tile, pad 4 (2-way only on reads)
    __shared__ float Bs[2048];         // packed W tile [kc][j][tx][4]

    const int tid = threadIdx.x;
    const int tx  = tid & 15;
    const int ty  = tid >> 4;
    const int bm  = blockIdx.x & 255;  // token block
    const int pp  = blockIdx.x >> 8;   // k-split part
    const int TILES = 64 / KS;         // k-tiles of 32 per block
    const int kt0 = pp * TILES;
    const int m0  = bm * 64;

    float acc[4][4] = {};

    for (int t = 0; t < TILES; t++) {
        const int kb = (kt0 + t) * 32;
        __syncthreads();   // protect LDS from previous tile's readers
        #pragma unroll
        for (int p = 0; p < 2; p++) {
            int lin = tid + p * 256;               // 0..511
            int m   = lin >> 3;
            int c4  = (lin & 7) << 2;
            *(float4*)&As[m][c4] =
                *(const float4*)&x[(size_t)(m0 + m) * CDIM + kb + c4];
        }
        const float* wsrc = Wp + (size_t)(kt0 + t) * 2048;
        #pragma unroll
        for (int p = 0; p < 2; p++) {
            int lin = tid + p * 256;
            *(float4*)&Bs[lin * 4] = *(const float4*)&wsrc[lin * 4];
        }
        __syncthreads();

        #pragma unroll
        for (int kc = 0; kc < 8; kc++) {
            float4 a[4], b[4];
            #pragma unroll
            for (int i = 0; i < 4; i++)
                a[i] = *(const float4*)&As[ty * 4 + i][kc * 4];
            #pragma unroll
            for (int j = 0; j < 4; j++)
                b[j] = *(const float4*)&Bs[((kc * 4 + j) * 16 + tx) * 4];
            #pragma unroll
            for (int i = 0; i < 4; i++)
                #pragma unroll
                for (int j = 0; j < 4; j++)
                    acc[i][j] += a[i].x * b[j].x + a[i].y * b[j].y
                               + a[i].z * b[j].z + a[i].w * b[j].w;
        }
    }

    float* dst = part + ((size_t)pp * NTOK + m0) * NEXP;
    #pragma unroll
    for (int i = 0; i < 4; i++) {
        int row = ty * 4 + i;
        float4 v = make_float4(acc[i][0], acc[i][1], acc[i][2], acc[i][3]);
        *(float4*)&dst[(size_t)row * NEXP + tx * 4] = v;
    }
}

// ============================================================================
// Kernel 3: top-8 + sigmoid + normalize + masked counts.
// 256 threads = 16 tokens x 16 lanes; parallel argmax via shfl_xor(<16).
// ============================================================================
template<int KS>
__global__ __launch_bounds__(256) void topk_kernel(
    const float* __restrict__ part,    // [KS][NTOK][NEXP]
    const int*   __restrict__ mask,    // [NTOK]
    const float* __restrict__ gbias,   // [NEXP]
    const float* __restrict__ ebias,   // [NEXP]
    float*       __restrict__ out,     // [2*NTOK*TOPK + 1]
    unsigned int* __restrict__ counts) // [NEXP]
{
    __shared__ unsigned int s_cnt[NEXP];
    const int tid = threadIdx.x;
    if (tid < NEXP) s_cnt[tid] = 0u;
    __syncthreads();

    const int t = blockIdx.x * 16 + (tid >> 4);  // token
    const int l = tid & 15;                      // lane within token group

    // sum k-split partials: this lane owns experts l*4 .. l*4+3
    float4 v = make_float4(0.f, 0.f, 0.f, 0.f);
    #pragma unroll
    for (int p = 0; p < KS; p++) {
        float4 u = *(const float4*)&part[((size_t)p * NTOK + t) * NEXP + l * 4];
        v.x += u.x; v.y += u.y; v.z += u.z; v.w += u.w;
    }
    float4 gb = *(const float4*)&gbias[l * 4];
    float4 eb = *(const float4*)&ebias[l * 4];
    float z[4], sel[4];
    z[0] = v.x + gb.x; z[1] = v.y + gb.y; z[2] = v.z + gb.z; z[3] = v.w + gb.w;
    sel[0] = z[0] + eb.x; sel[1] = z[1] + eb.y;
    sel[2] = z[2] + eb.z; sel[3] = z[3] + eb.w;

    int   idxs[TOPK];
    float probs[TOPK];
    float psum = 0.f;

    #pragma unroll
    for (int r = 0; r < TOPK; r++) {
        // local argmax over this lane's unused experts
        float bv = -INFINITY; float bz = 0.f; int bidx = 1 << 30;
        #pragma unroll
        for (int i = 0; i < 4; i++) {
            if (sel[i] > bv) { bv = sel[i]; bz = z[i]; bidx = l * 4 + i; }
        }
        // reduce across the 16-lane token group (xor<16 stays in-group)
        #pragma unroll
        for (int m = 1; m < 16; m <<= 1) {
            float ov = __shfl_xor(bv, m);
            float oz = __shfl_xor(bz, m);
            int   oi = __shfl_xor(bidx, m);
            if (ov > bv || (ov == bv && oi < bidx)) { bv = ov; bz = oz; bidx = oi; }
        }
        idxs[r] = bidx;
        float p = 1.f / (1.f + expf(-bz));
        probs[r] = p;
        psum += p;
        if ((bidx >> 2) == l) sel[bidx & 3] = -INFINITY;  // mark used
    }

    float inv = 1.f / psum;
    if (l < TOPK) {
        out[(size_t)t * TOPK + l] = (float)idxs[l];
        out[(size_t)NTOK * TOPK + (size_t)t * TOPK + l] = probs[l] * inv;
        if (mask[t] != 0) atomicAdd(&s_cnt[idxs[l]], 1u);
    }
    __syncthreads();
    if (tid < NEXP && s_cnt[tid] != 0u) atomicAdd(&counts[tid], s_cnt[tid]);
}

__global__ void finalize_kernel(const unsigned int* __restrict__ counts,
                                float* __restrict__ out)
{
    const int t = threadIdx.x;   // 64 threads, one wave
    float c  = (float)counts[t];
    float mx = c, sm = c;
    #pragma unroll
    for (int o = 32; o > 0; o >>= 1) {
        mx = fmaxf(mx, __shfl_down(mx, o));
        sm += __shfl_down(sm, o);
    }
    if (t == 0) {
        float avg = sm / (float)NEXP;
        out[2 * NTOK * TOPK] = (mx - avg) / (avg + 1e-5f);
    }
}

// ============================================================================
// Fallback (ws too small): round-1 fused kernel, known-correct.
// ============================================================================
__global__ __launch_bounds__(256) void fused_fallback_kernel(
    const float* __restrict__ x, const int* __restrict__ mask,
    const float* __restrict__ W, const float* __restrict__ gbias,
    const float* __restrict__ ebias, float* __restrict__ out,
    unsigned int* __restrict__ counts)
{
    __shared__ float As[64][36];
    __shared__ float Bs[64][36];
    __shared__ float Lg[64][NEXP + 1];
    __shared__ float s_gb[NEXP], s_eb[NEXP];
    __shared__ unsigned int s_cnt[NEXP];

    const int tid = threadIdx.x;
    const int tx = tid & 15, ty = tid >> 4;
    const int m0 = blockIdx.x * 64;
    if (tid < NEXP) { s_gb[tid] = gbias[tid]; s_eb[tid] = ebias[tid]; s_cnt[tid] = 0u; }
    float acc[4][4] = {};
    for (int kb = 0; kb < CDIM; kb += 32) {
        __syncthreads();
        #pragma unroll
        for (int p = 0; p < 2; p++) {
            int lin = tid + p * 256; int m = lin >> 3; int c4 = (lin & 7) << 2;
            *(float4*)&As[m][c4] = *(const float4*)&x[(size_t)(m0 + m) * CDIM + kb + c4];
            *(float4*)&Bs[m][c4] = *(const float4*)&W[(size_t)m * CDIM + kb + c4];
        }
        __syncthreads();
        #pragma unroll
        for (int k4 = 0; k4 < 32; k4 += 4) {
            float4 a[4], b[4];
            #pragma unroll
            for (int i = 0; i < 4; i++) a[i] = *(const float4*)&As[ty * 4 + i][k4];
            #pragma unroll
            for (int j = 0; j < 4; j++) b[j] = *(const float4*)&Bs[tx * 4 + j][k4];
            #pragma unroll
            for (int i = 0; i < 4; i++)
                #pragma unroll
                for (int j = 0; j < 4; j++)
                    acc[i][j] += a[i].x * b[j].x + a[i].y * b[j].y
                               + a[i].z * b[j].z + a[i].w * b[j].w;
        }
    }
    __syncthreads();
    #pragma unroll
    for (int i = 0; i < 4; i++)
        #pragma unroll
        for (int j = 0; j < 4; j++)
            Lg[ty * 4 + i][tx * 4 + j] = acc[i][j] + s_gb[tx * 4 + j];
    __syncthreads();
    if (tid < 64) {
        const int g = m0 + tid;
        unsigned long long used = 0ull;
        int idxs[TOPK]; float probs[TOPK]; float psum = 0.f;
        #pragma unroll
        for (int k = 0; k < TOPK; k++) {
            float best = -INFINITY; int bi = 0;
            for (int n = 0; n < NEXP; n++) {
                if ((used >> n) & 1ull) continue;
                float vv = Lg[tid][n] + s_eb[n];
                if (vv > best) { best = vv; bi = n; }
            }
            used |= (1ull << bi);
            idxs[k] = bi;
            float p = 1.f / (1.f + expf(-Lg[tid][bi]));
            probs[k] = p; psum += p;
        }
        float inv = 1.f / psum;
        #pragma unroll
        for (int k = 0; k < TOPK; k++) {
            out[(size_t)g * TOPK + k] = (float)idxs[k];
            out[(size_t)NTOK * TOPK + (size_t)g * TOPK + k] = probs[k] * inv;
        }
        if (mask[g] != 0)
            #pragma unroll
            for (int k = 0; k < TOPK; k++) atomicAdd(&s_cnt[idxs[k]], 1u);
    }
    __syncthreads();
    if (tid < NEXP && s_cnt[tid] != 0u) atomicAdd(&counts[tid], s_cnt[tid]);
}

extern "C" void kernel_launch(void* const* d_in, const int* in_sizes, int n_in,
                              void* d_out, int out_size, void* d_ws, size_t ws_size,
                              hipStream_t stream)
{
    const float* x     = (const float*)d_in[0];
    const int*   mask  = (const int*)  d_in[1];
    const float* W     = (const float*)d_in[2];
    const float* gbias = (const float*)d_in[3];
    const float* ebias = (const float*)d_in[4];
    float* out = (float*)d_out;

    // ws layout: [64 uint counts (256 B)][KS*NTOK*NEXP f32 partials][Wp 512 KB]
    unsigned int* counts = (unsigned int*)d_ws;
    float* part = (float*)((char*)d_ws + 256);

    const size_t partB1 = (size_t)NTOK * NEXP * sizeof(float);  // 4 MB per split
    const size_t wpB    = (size_t)NEXP * CDIM * sizeof(float);  // 512 KB
    auto need = [&](int ks) { return 256 + (size_t)ks * partB1 + wpB; };

    int KS = 0;
    if      (ws_size >= need(4)) KS = 4;
    else if (ws_size >= need(2)) KS = 2;
    else if (ws_size >= need(1)) KS = 1;

    hipMemsetAsync(d_ws, 0, 256, stream);

    if (KS == 0) {
        fused_fallback_kernel<<<NTOK / 64, 256, 0, stream>>>(
            x, mask, W, gbias, ebias, out, counts);
        finalize_kernel<<<1, 64, 0, stream>>>(counts, out);
        return;
    }

    float* Wp = (float*)((char*)d_ws + 256 + (size_t)KS * partB1);
    pack_w_kernel<<<128, 256, 0, stream>>>(W, Wp);

    if (KS == 4) {
        gemm_partial_kernel<4><<<256 * 4, 256, 0, stream>>>(x, Wp, part);
        topk_kernel<4><<<NTOK / 16, 256, 0, stream>>>(part, mask, gbias, ebias, out, counts);
    } else if (KS == 2) {
        gemm_partial_kernel<2><<<256 * 2, 256, 0, stream>>>(x, Wp, part);
        topk_kernel<2><<<NTOK / 16, 256, 0, stream>>>(part, mask, gbias, ebias, out, counts);
    } else {
        gemm_partial_kernel<1><<<256 * 1, 256, 0, stream>>>(x, Wp, part);
        topk_kernel<1><<<NTOK / 16, 256, 0, stream>>>(part, mask, gbias, ebias, out, counts);
    }
    finalize_kernel<<<1, 64, 0, stream>>>(counts, out);
}